// Round 15
// baseline (162.154 us; speedup 1.0000x reference)
//
#include <hip/hip_runtime.h>
#include <hip/hip_bf16.h>

#define B_ 4
#define S_ 2048
#define D_ 1024
#define H_ 16
#define HD_ 64
#define M_TOK 8192   // B*S
#define QSCALE 0.18033688f   // 0.125 * log2(e)

typedef __attribute__((ext_vector_type(4))) float f32x4;
typedef __attribute__((ext_vector_type(4))) int int4_t;
typedef __attribute__((ext_vector_type(8))) short short8;
typedef __attribute__((ext_vector_type(4))) short short4_t;

__device__ inline short f2bf(float f) {
  unsigned u = __builtin_bit_cast(unsigned, f);
  u += 0x7fff + ((u >> 16) & 1);   // RNE
  return (short)(u >> 16);
}
__device__ inline short f2bf_trunc(float f) {
  return (short)(__builtin_bit_cast(unsigned, f) >> 16);
}
__device__ inline unsigned pack_bf16_trunc(float lo, float hi) {
  return __builtin_amdgcn_perm(__builtin_bit_cast(unsigned, hi),
                               __builtin_bit_cast(unsigned, lo), 0x07060302u);
}

typedef __attribute__((address_space(1))) const unsigned int gas_u32;
typedef __attribute__((address_space(3))) unsigned int las_u32;
__device__ inline void gload_lds16(const void* g, void* l) {
  __builtin_amdgcn_global_load_lds((gas_u32*)g, (las_u32*)l, 16, 0, 0);
}

// Fragment-packed layouts:
//   Q/K (per bh plane): idx(s,e) = (s>>4)*1024 + (e>>3)*128 + (s&15)*8 + (e&7)
//   V   (per bh plane): idx(hd,s) = ((hd>>4)*64+(s>>5))*512 + ((s>>2)&3)*128
//                                   + (hd&15)*8 + (s&3)*2 + ((s>>4)&1)
//   W packed [N][K]:    idx(n,k) = (n>>4)*16384 + (k>>5)*512 + ((k>>3)&3)*128 + (n&15)*8 + (k&7)

// ---------------- conversion kernels ----------------
__global__ __launch_bounds__(256) void conv_x_kernel(
    const float* __restrict__ x, short* __restrict__ xb) {
  size_t base = ((size_t)blockIdx.x * 256 + threadIdx.x) * 8;
  f32x4 v0 = *reinterpret_cast<const f32x4*>(&x[base]);
  f32x4 v1 = *reinterpret_cast<const f32x4*>(&x[base + 4]);
  short8 o;
  o[0]=f2bf(v0[0]); o[1]=f2bf(v0[1]); o[2]=f2bf(v0[2]); o[3]=f2bf(v0[3]);
  o[4]=f2bf(v1[0]); o[5]=f2bf(v1[1]); o[6]=f2bf(v1[2]); o[7]=f2bf(v1[3]);
  *reinterpret_cast<short8*>(&xb[base]) = o;
}

__global__ __launch_bounds__(256) void conv_wqkv_kernel(
    const float* __restrict__ Wqkv, short* __restrict__ wp) {
  const int h = blockIdx.x;
  const int k0 = blockIdx.y * 32;
  const int tid = threadIdx.x;
  __shared__ short T[192 * 40];
#pragma unroll
  for (int i = 0; i < 6; ++i) {
    int iv = tid + i * 256;
    int k = iv / 48;
    int e4 = (iv % 48) * 4;
    f32x4 v = *reinterpret_cast<const f32x4*>(&Wqkv[((size_t)h * D_ + k0 + k) * 192 + e4]);
#pragma unroll
    for (int j = 0; j < 4; ++j) T[(e4 + j) * 40 + k] = f2bf(v[j]);
  }
  __syncthreads();
#pragma unroll
  for (int i = 0; i < 3; ++i) {
    int u = tid + i * 256;
    int e16 = u >> 6;
    int rem = u & 63;
    int e = e16 * 16 + (rem & 15);
    int k8 = (rem >> 4) * 8;
    short8 o = *reinterpret_cast<const short8*>(&T[e * 40 + k8]);
    *reinterpret_cast<short8*>(
        &wp[(size_t)(h * 12 + e16) * 16384 + blockIdx.y * 512 + rem * 8]) = o;
  }
}

__global__ __launch_bounds__(256) void conv_wo_kernel(
    const float* __restrict__ Wo, short* __restrict__ wp) {
  const int k0 = blockIdx.x * 32;
  const int n0 = blockIdx.y * 128;
  const int tid = threadIdx.x;
  __shared__ short T[128 * 40];
#pragma unroll
  for (int i = 0; i < 4; ++i) {
    int iv = tid + i * 256;
    int k = iv >> 5;
    int n4 = (iv & 31) * 4;
    f32x4 v = *reinterpret_cast<const f32x4*>(&Wo[(size_t)(k0 + k) * 1024 + n0 + n4]);
#pragma unroll
    for (int j = 0; j < 4; ++j) T[(n4 + j) * 40 + k] = f2bf(v[j]);
  }
  __syncthreads();
#pragma unroll
  for (int i = 0; i < 2; ++i) {
    int u = tid + i * 256;
    int ntile = u >> 6;
    int rem = u & 63;
    short8 o = *reinterpret_cast<const short8*>(
        &T[(ntile * 16 + (rem & 15)) * 40 + (rem >> 4) * 8]);
    *reinterpret_cast<short8*>(
        &wp[(size_t)((n0 >> 4) + ntile) * 16384 + blockIdx.x * 512 + rem * 8]) = o;
  }
}

// ---------------- GEMM: A via 4-buf LDS, B direct from packed global ----------------
// r12-proven schedule: two barriers per K-step (2nd barrier guarantees every wave's
// VMW(6) retired before anyone's COMP reads the freshly staged buffer — required
// in the first two iterations where no prior-step VMW exists).
template<int EPI>
__global__ __launch_bounds__(256, 3) void gemm4_kernel(
    const short* __restrict__ A, const short* __restrict__ Bp,
    const float* __restrict__ bias,
    short* __restrict__ qb, short* __restrict__ kb, short* __restrict__ vt,
    float* __restrict__ out) {
  constexpr int KD = 1024;
  const int m0 = blockIdx.x * 128;
  const int n0 = blockIdx.y * 128;
  const int tid = threadIdx.x;
  const int lane = tid & 63, wv = tid >> 6;
  const int wr = wv >> 1, wc = wv & 1;
  const int g = lane >> 4, c = lane & 15;

  __shared__ short As[4 * 4096];   // 32 KB

  const f32x4 zero4 = {0.f, 0.f, 0.f, 0.f};
  f32x4 acc[4][4];
#pragma unroll
  for (int i = 0; i < 4; ++i)
#pragma unroll
    for (int j = 0; j < 4; ++j) acc[i][j] = zero4;

  const short* bbase = Bp + (size_t)((n0 + wc * 64) >> 4) * 16384 + lane * 8;
  short8 bb0[4], bb1[4];

  auto LOADB = [&](int t, short8* br) {
#pragma unroll
    for (int nt = 0; nt < 4; ++nt)
      br[nt] = *reinterpret_cast<const short8*>(&bbase[(size_t)nt * 16384 + t * 512]);
  };
  auto STAGE = [&](int kt, int buf) {
    const short* asrc = A + (size_t)m0 * KD + kt * 32;
#pragma unroll
    for (int i = 0; i < 2; ++i) {
      int ch = tid + i * 256;
      int row = ch >> 2;
      int slot = (ch & 3) ^ ((row >> 1) & 3);
      gload_lds16(asrc + (size_t)row * KD + slot * 8, &As[buf * 4096 + ch * 8]);
    }
  };
  const int sread = (g ^ ((c >> 1) & 3)) * 8;
  auto COMP = [&](int buf, short8* br) {
    const short* Ab = &As[buf * 4096];
    short8 a[4];
#pragma unroll
    for (int mt = 0; mt < 4; ++mt)
      a[mt] = *reinterpret_cast<const short8*>(&Ab[(wr * 64 + mt * 16 + c) * 32 + sread]);
    __builtin_amdgcn_s_setprio(1);
#pragma unroll
    for (int mt = 0; mt < 4; ++mt)
#pragma unroll
      for (int nt = 0; nt < 4; ++nt)
        acc[mt][nt] = __builtin_amdgcn_mfma_f32_16x16x32_bf16(a[mt], br[nt], acc[mt][nt], 0, 0, 0);
    __builtin_amdgcn_s_setprio(0);
  };

#define BAR1 __builtin_amdgcn_sched_barrier(0); __builtin_amdgcn_s_barrier(); __builtin_amdgcn_sched_barrier(0)
#define VMW(N) asm volatile("s_waitcnt vmcnt(" #N ")" ::: "memory")

  STAGE(0, 0); STAGE(1, 1); LOADB(0, bb0);

#pragma unroll 1
  for (int p = 0; p < 7; ++p) {
    const int tb = p * 4;
    BAR1; STAGE(tb + 2, 2); LOADB(tb + 1, bb1); VMW(6); BAR1; COMP(0, bb0);
    BAR1; STAGE(tb + 3, 3); LOADB(tb + 2, bb0); VMW(6); BAR1; COMP(1, bb1);
    BAR1; STAGE(tb + 4, 0); LOADB(tb + 3, bb1); VMW(6); BAR1; COMP(2, bb0);
    BAR1; STAGE(tb + 5, 1); LOADB(tb + 4, bb0); VMW(6); BAR1; COMP(3, bb1);
  }
  BAR1; STAGE(30, 2); LOADB(29, bb1); VMW(6); BAR1; COMP(0, bb0);   // t=28
  BAR1; STAGE(31, 3); LOADB(30, bb0); VMW(6); BAR1; COMP(1, bb1);   // t=29
  BAR1;               LOADB(31, bb1); VMW(4); BAR1; COMP(2, bb0);   // t=30
  BAR1;                               VMW(0); BAR1; COMP(3, bb1);   // t=31

#undef BAR1
#undef VMW

  // ---- epilogue ----
  if (EPI == 0) {
#pragma unroll
    for (int nt = 0; nt < 4; ++nt) {
      int n = n0 + wc * 64 + nt * 16 + c;
      float bv = bias[n];
      int h = n / 192, e = n % 192;
      if (e < 128) {
#pragma unroll
        for (int mt = 0; mt < 4; ++mt) {
          int m_base = m0 + wr * 64 + mt * 16 + g * 4;
          int bb2 = m_base >> 11, s0 = m_base & 2047;
          size_t plane = (size_t)(bb2 * H_ + h) * (S_ * HD_);
          if (e < 64) {
            size_t bp = plane + (size_t)(s0 >> 4) * 1024 + (e >> 3) * 128 + (s0 & 15) * 8 + (e & 7);
#pragma unroll
            for (int r = 0; r < 4; ++r)
              qb[bp + r * 8] = f2bf((acc[mt][nt][r] + bv) * QSCALE);
          } else {
            int ek = e - 64;
            size_t bp = plane + (size_t)(s0 >> 4) * 1024 + (ek >> 3) * 128 + (s0 & 15) * 8 + (ek & 7);
#pragma unroll
            for (int r = 0; r < 4; ++r)
              kb[bp + r * 8] = f2bf(acc[mt][nt][r] + bv);
          }
        }
      } else {
        int hd = e - 128;
#pragma unroll
        for (int mtp = 0; mtp < 2; ++mtp) {
          int mt = mtp * 2;
          int m_base = m0 + wr * 64 + mt * 16 + g * 4;
          int bb2 = m_base >> 11, s0 = m_base & 2047;
          size_t plane = (size_t)(bb2 * H_ + h) * (S_ * HD_);
          size_t bp = plane + (size_t)((hd >> 4) * 64 + (s0 >> 5)) * 512 +
                      ((s0 >> 2) & 3) * 128 + (hd & 15) * 8;
          int4_t pk;
#pragma unroll
          for (int r = 0; r < 4; ++r)
            pk[r] = (int)pack_bf16_trunc(acc[mt][nt][r] + bv, acc[mt + 1][nt][r] + bv);
          *reinterpret_cast<int4_t*>(&vt[bp]) = pk;
        }
      }
    }
  } else {
#pragma unroll
    for (int mt = 0; mt < 4; ++mt) {
#pragma unroll
      for (int nt = 0; nt < 4; ++nt) {
        int n = n0 + wc * 64 + nt * 16 + c;
        float bv = bias[n];
        int m_base = m0 + wr * 64 + mt * 16 + g * 4;
#pragma unroll
        for (int r = 0; r < 4; ++r)
          out[(size_t)(m_base + r) * D_ + n] = acc[mt][nt][r] + bv;
      }
    }
  }
}

// ---------------- causal flash attention: paired 8-wave blocks ----------------
// Block = q-tile pair (15-p, p): waves 0-3 -> long tile, 4-7 -> short tile.
// SIMD s gets waves {s, s+4} whose k-tile counts sum to 62+2s — uniform across
// all SIMDs of all CUs -> no drain tail. 512 blocks x 8 waves = 16 waves/CU.
struct KF32 { short8 f[4]; };

__device__ __forceinline__ void load_kf32(KF32& k, const short* __restrict__ kbh,
                                          int ktb, int lane) {
#pragma unroll
  for (int cc = 0; cc < 2; ++cc)
#pragma unroll
    for (int t = 0; t < 2; ++t)
      k.f[cc * 2 + t] = *reinterpret_cast<const short8*>(
          &kbh[(size_t)(ktb * 2 + t) * 1024 + cc * 512 + lane * 8]);
}

__global__ __launch_bounds__(512, 4) void attn_kernel(
    const short* __restrict__ qb, const short* __restrict__ kb,
    const short* __restrict__ vt, short* __restrict__ av) {
  const int orig = blockIdx.x;            // 512 blocks
  const int xcd = orig & 7;
  const int local = orig >> 3;            // 0..63
  const int bh = xcd * 8 + (local & 7);   // bh fastest: KV octet per XCD
  const int pr = local >> 3;              // 0..7
  const int bb = bh >> 4, h = bh & 15;
  const int tid = threadIdx.x;
  const int lane = tid & 63, wv = tid >> 6;   // 0..7
  const int wv4 = wv & 3;
  const int qt = (wv >> 2) ? pr : 15 - pr;    // paired q-tiles in one block
  const int g = lane >> 4, c = lane & 15;
  const int q0 = qt * 128;
  const int r0 = q0 + wv4 * 32;

  __shared__ short Ps[8][32 * 40];
  short* Pw = Ps[wv];
  unsigned* Pw32 = reinterpret_cast<unsigned*>(Pw);

  const short* qbh = qb + (size_t)bh * S_ * HD_;
  const short* kbh = kb + (size_t)bh * S_ * HD_;
  const short* vth = vt + (size_t)bh * HD_ * S_;

  short8 ones;
#pragma unroll
  for (int j = 0; j < 8; ++j) ones[j] = (short)0x3F80;

  const f32x4 zero4 = {0.f, 0.f, 0.f, 0.f};

  short8 qf[2][2];
#pragma unroll
  for (int mt = 0; mt < 2; ++mt)
#pragma unroll
    for (int cc = 0; cc < 2; ++cc)
      qf[mt][cc] = *reinterpret_cast<const short8*>(
          &qbh[(size_t)(r0 / 16 + mt) * 1024 + cc * 512 + lane * 8]);

  f32x4 acc_o[2][4];
  f32x4 lacc[2];
#pragma unroll
  for (int mt = 0; mt < 2; ++mt) {
    lacc[mt] = zero4;
#pragma unroll
    for (int nt = 0; nt < 4; ++nt) acc_o[mt][nt] = zero4;
  }

  const int diag = 4 * qt + wv4;
  const int nk = diag + 1;

  KF32 kA, kB;
  load_kf32(kA, kbh, 0, lane);

  auto body = [&](int ktb, KF32& kc, KF32& kn) {
    const int k0 = ktb * 32;
    short8 vf[4];
#pragma unroll
    for (int nt = 0; nt < 4; ++nt)
      vf[nt] = *reinterpret_cast<const short8*>(
          &vth[(size_t)(nt * 64 + ktb) * 512 + lane * 8]);
    f32x4 sc[2][2];
#pragma unroll
    for (int mt = 0; mt < 2; ++mt)
#pragma unroll
      for (int t = 0; t < 2; ++t) sc[mt][t] = zero4;
#pragma unroll
    for (int cc = 0; cc < 2; ++cc)
#pragma unroll
      for (int mt = 0; mt < 2; ++mt)
#pragma unroll
        for (int t = 0; t < 2; ++t)
          sc[mt][t] = __builtin_amdgcn_mfma_f32_16x16x32_bf16(
              qf[mt][cc], kc.f[cc * 2 + t], sc[mt][t], 0, 0, 0);
    int ktbn = ktb + 1;
    if (ktbn >= S_ / 32) ktbn = 0;
    load_kf32(kn, kbh, ktbn, lane);
    if (ktb == diag) {
#pragma unroll
      for (int mt = 0; mt < 2; ++mt)
#pragma unroll
        for (int t = 0; t < 2; ++t) {
          const int key = k0 + t * 16 + c;
#pragma unroll
          for (int r = 0; r < 4; ++r) {
            const int qi2 = r0 + mt * 16 + g * 4 + r;
            if (key > qi2) sc[mt][t][r] = -INFINITY;
          }
        }
    }
#pragma unroll
    for (int mt = 0; mt < 2; ++mt)
#pragma unroll
      for (int r = 0; r < 4; ++r) {
        float p0 = __builtin_exp2f(sc[mt][0][r]);
        float p1 = __builtin_exp2f(sc[mt][1][r]);
        Pw32[(mt * 16 + g * 4 + r) * 20 + c] = pack_bf16_trunc(p0, p1);
      }
    short8 pa[2];
#pragma unroll
    for (int mt = 0; mt < 2; ++mt)
      pa[mt] = *reinterpret_cast<const short8*>(&Pw[(mt * 16 + c) * 40 + g * 8]);
#pragma unroll
    for (int mt = 0; mt < 2; ++mt)
      lacc[mt] = __builtin_amdgcn_mfma_f32_16x16x32_bf16(pa[mt], ones, lacc[mt], 0, 0, 0);
#pragma unroll
    for (int mt = 0; mt < 2; ++mt)
#pragma unroll
      for (int nt = 0; nt < 4; ++nt)
        acc_o[mt][nt] = __builtin_amdgcn_mfma_f32_16x16x32_bf16(
            pa[mt], vf[nt], acc_o[mt][nt], 0, 0, 0);
  };

  int ktb = 0;
  for (; ktb + 1 < nk; ktb += 2) {
    body(ktb,     kA, kB);
    body(ktb + 1, kB, kA);
  }
  if (ktb < nk) body(ktb, kA, kB);

#pragma unroll
  for (int mt = 0; mt < 2; ++mt) {
    float inv[4];
#pragma unroll
    for (int r = 0; r < 4; ++r) inv[r] = 1.0f / lacc[mt][r];
#pragma unroll
    for (int nt = 0; nt < 4; ++nt)
#pragma unroll
      for (int r = 0; r < 4; ++r) {
        int R = r0 + mt * 16 + g * 4 + r;
        av[(size_t)(bb * S_ + R) * D_ + h * HD_ + nt * 16 + c] =
            f2bf(acc_o[mt][nt][r] * inv[r]);
      }
  }
}

extern "C" void kernel_launch(void* const* d_in, const int* in_sizes, int n_in,
                              void* d_out, int out_size, void* d_ws, size_t ws_size,
                              hipStream_t stream) {
  const float* x    = (const float*)d_in[0];
  const float* Wqkv = (const float*)d_in[1];
  const float* bqkv = (const float*)d_in[2];
  const float* Wo   = (const float*)d_in[3];
  const float* bo   = (const float*)d_in[4];
  float* out = (float*)d_out;

  const size_t NTOK = (size_t)B_ * H_ * S_ * HD_;  // 8,388,608
  short* xb    = (short*)d_ws;                     // 16 MB
  short* wqkvt = xb + (size_t)M_TOK * D_;          // 6 MB (packed)
  short* wot   = wqkvt + (size_t)3072 * 1024;      // 2 MB (packed)
  short* qb    = wot + (size_t)1024 * 1024;        // 16 MB
  short* kb    = qb + NTOK;                        // 16 MB
  short* vt    = kb + NTOK;                        // 16 MB
  short* av    = xb;                               // alias: xb dead after qkv GEMM

  conv_x_kernel   <<<4096, 256, 0, stream>>>(x, xb);
  conv_wqkv_kernel<<<dim3(16, 32), 256, 0, stream>>>(Wqkv, wqkvt);
  conv_wo_kernel  <<<dim3(32, 8), 256, 0, stream>>>(Wo, wot);
  gemm4_kernel<0> <<<dim3(64, 24), 256, 0, stream>>>(xb, wqkvt, bqkv, qb, kb, vt, nullptr);
  attn_kernel     <<<512, 512, 0, stream>>>(qb, kb, vt, av);
  gemm4_kernel<1> <<<dim3(64, 8), 256, 0, stream>>>(av, wot, bo, nullptr, nullptr, nullptr, out);
}

// Round 16
// 159.556 us; speedup vs baseline: 1.0163x; 1.0163x over previous
//
#include <hip/hip_runtime.h>
#include <hip/hip_bf16.h>

#define B_ 4
#define S_ 2048
#define D_ 1024
#define H_ 16
#define HD_ 64
#define M_TOK 8192   // B*S
#define QSCALE 0.18033688f   // 0.125 * log2(e)

typedef __attribute__((ext_vector_type(4))) float f32x4;
typedef __attribute__((ext_vector_type(4))) int int4_t;
typedef __attribute__((ext_vector_type(8))) short short8;
typedef __attribute__((ext_vector_type(4))) short short4_t;

__device__ inline short f2bf(float f) {
  unsigned u = __builtin_bit_cast(unsigned, f);
  u += 0x7fff + ((u >> 16) & 1);   // RNE
  return (short)(u >> 16);
}
__device__ inline short f2bf_trunc(float f) {
  return (short)(__builtin_bit_cast(unsigned, f) >> 16);
}
__device__ inline unsigned pack_bf16_trunc(float lo, float hi) {
  return __builtin_amdgcn_perm(__builtin_bit_cast(unsigned, hi),
                               __builtin_bit_cast(unsigned, lo), 0x07060302u);
}

typedef __attribute__((address_space(1))) const unsigned int gas_u32;
typedef __attribute__((address_space(3))) unsigned int las_u32;
__device__ inline void gload_lds16(const void* g, void* l) {
  __builtin_amdgcn_global_load_lds((gas_u32*)g, (las_u32*)l, 16, 0, 0);
}

// Fragment-packed layouts:
//   Q/K (per bh plane): idx(s,e) = (s>>4)*1024 + (e>>3)*128 + (s&15)*8 + (e&7)
//   V   (per bh plane): idx(hd,s) = ((hd>>4)*64+(s>>5))*512 + ((s>>2)&3)*128
//                                   + (hd&15)*8 + (s&3)*2 + ((s>>4)&1)
//   W packed [N][K]:    idx(n,k) = (n>>4)*16384 + (k>>5)*512 + ((k>>3)&3)*128 + (n&15)*8 + (k&7)

// ---------------- conversion kernels ----------------
__global__ __launch_bounds__(256) void conv_x_kernel(
    const float* __restrict__ x, short* __restrict__ xb) {
  size_t base = ((size_t)blockIdx.x * 256 + threadIdx.x) * 8;
  f32x4 v0 = *reinterpret_cast<const f32x4*>(&x[base]);
  f32x4 v1 = *reinterpret_cast<const f32x4*>(&x[base + 4]);
  short8 o;
  o[0]=f2bf(v0[0]); o[1]=f2bf(v0[1]); o[2]=f2bf(v0[2]); o[3]=f2bf(v0[3]);
  o[4]=f2bf(v1[0]); o[5]=f2bf(v1[1]); o[6]=f2bf(v1[2]); o[7]=f2bf(v1[3]);
  *reinterpret_cast<short8*>(&xb[base]) = o;
}

__global__ __launch_bounds__(256) void conv_wqkv_kernel(
    const float* __restrict__ Wqkv, short* __restrict__ wp) {
  const int h = blockIdx.x;
  const int k0 = blockIdx.y * 32;
  const int tid = threadIdx.x;
  __shared__ short T[192 * 40];
#pragma unroll
  for (int i = 0; i < 6; ++i) {
    int iv = tid + i * 256;
    int k = iv / 48;
    int e4 = (iv % 48) * 4;
    f32x4 v = *reinterpret_cast<const f32x4*>(&Wqkv[((size_t)h * D_ + k0 + k) * 192 + e4]);
#pragma unroll
    for (int j = 0; j < 4; ++j) T[(e4 + j) * 40 + k] = f2bf(v[j]);
  }
  __syncthreads();
#pragma unroll
  for (int i = 0; i < 3; ++i) {
    int u = tid + i * 256;
    int e16 = u >> 6;
    int rem = u & 63;
    int e = e16 * 16 + (rem & 15);
    int k8 = (rem >> 4) * 8;
    short8 o = *reinterpret_cast<const short8*>(&T[e * 40 + k8]);
    *reinterpret_cast<short8*>(
        &wp[(size_t)(h * 12 + e16) * 16384 + blockIdx.y * 512 + rem * 8]) = o;
  }
}

__global__ __launch_bounds__(256) void conv_wo_kernel(
    const float* __restrict__ Wo, short* __restrict__ wp) {
  const int k0 = blockIdx.x * 32;
  const int n0 = blockIdx.y * 128;
  const int tid = threadIdx.x;
  __shared__ short T[128 * 40];
#pragma unroll
  for (int i = 0; i < 4; ++i) {
    int iv = tid + i * 256;
    int k = iv >> 5;
    int n4 = (iv & 31) * 4;
    f32x4 v = *reinterpret_cast<const f32x4*>(&Wo[(size_t)(k0 + k) * 1024 + n0 + n4]);
#pragma unroll
    for (int j = 0; j < 4; ++j) T[(n4 + j) * 40 + k] = f2bf(v[j]);
  }
  __syncthreads();
#pragma unroll
  for (int i = 0; i < 2; ++i) {
    int u = tid + i * 256;
    int ntile = u >> 6;
    int rem = u & 63;
    short8 o = *reinterpret_cast<const short8*>(
        &T[(ntile * 16 + (rem & 15)) * 40 + (rem >> 4) * 8]);
    *reinterpret_cast<short8*>(
        &wp[(size_t)((n0 >> 4) + ntile) * 16384 + blockIdx.x * 512 + rem * 8]) = o;
  }
}

// ---------------- GEMM: A via 4-buf LDS, B 3-set register pipeline (distance 2) ----------------
// Per step t: BAR; STAGE(t+2)+LOADB(t+2); VMW(12) retires exactly S(t)+B(t); BAR; COMP(t).
// S and B both get 2 full steps of latency slack; two barriers as proven in r12/r14.
template<int EPI>
__global__ __launch_bounds__(256, 3) void gemm4_kernel(
    const short* __restrict__ A, const short* __restrict__ Bp,
    const float* __restrict__ bias,
    short* __restrict__ qb, short* __restrict__ kb, short* __restrict__ vt,
    float* __restrict__ out) {
  constexpr int KD = 1024;
  const int m0 = blockIdx.x * 128;
  const int n0 = blockIdx.y * 128;
  const int tid = threadIdx.x;
  const int lane = tid & 63, wv = tid >> 6;
  const int wr = wv >> 1, wc = wv & 1;
  const int g = lane >> 4, c = lane & 15;

  __shared__ short As[4 * 4096];   // 32 KB

  const f32x4 zero4 = {0.f, 0.f, 0.f, 0.f};
  f32x4 acc[4][4];
#pragma unroll
  for (int i = 0; i < 4; ++i)
#pragma unroll
    for (int j = 0; j < 4; ++j) acc[i][j] = zero4;

  const short* bbase = Bp + (size_t)((n0 + wc * 64) >> 4) * 16384 + lane * 8;
  short8 bb0[4], bb1[4], bb2[4];

  auto LOADB = [&](int t, short8* br) {
#pragma unroll
    for (int nt = 0; nt < 4; ++nt)
      br[nt] = *reinterpret_cast<const short8*>(&bbase[(size_t)nt * 16384 + t * 512]);
  };
  auto STAGE = [&](int kt, int buf) {
    const short* asrc = A + (size_t)m0 * KD + kt * 32;
#pragma unroll
    for (int i = 0; i < 2; ++i) {
      int ch = tid + i * 256;
      int row = ch >> 2;
      int slot = (ch & 3) ^ ((row >> 1) & 3);
      gload_lds16(asrc + (size_t)row * KD + slot * 8, &As[buf * 4096 + ch * 8]);
    }
  };
  const int sread = (g ^ ((c >> 1) & 3)) * 8;
  auto COMP = [&](int buf, short8* br) {
    const short* Ab = &As[buf * 4096];
    short8 a[4];
#pragma unroll
    for (int mt = 0; mt < 4; ++mt)
      a[mt] = *reinterpret_cast<const short8*>(&Ab[(wr * 64 + mt * 16 + c) * 32 + sread]);
    __builtin_amdgcn_s_setprio(1);
#pragma unroll
    for (int mt = 0; mt < 4; ++mt)
#pragma unroll
      for (int nt = 0; nt < 4; ++nt)
        acc[mt][nt] = __builtin_amdgcn_mfma_f32_16x16x32_bf16(a[mt], br[nt], acc[mt][nt], 0, 0, 0);
    __builtin_amdgcn_s_setprio(0);
  };

#define BAR1 __builtin_amdgcn_sched_barrier(0); __builtin_amdgcn_s_barrier(); __builtin_amdgcn_sched_barrier(0)
#define VMW(N) asm volatile("s_waitcnt vmcnt(" #N ")" ::: "memory")
#define GSTEP(T2, SB, BBN, CB, BBC) \
  BAR1; STAGE(T2, SB); LOADB(T2, BBN); VMW(12); BAR1; COMP(CB, BBC);

  STAGE(0, 0); STAGE(1, 1); LOADB(0, bb0); LOADB(1, bb1);

  GSTEP(2, 2, bb2, 0, bb0)    // t=0
  GSTEP(3, 3, bb0, 1, bb1)    // t=1
  GSTEP(4, 0, bb1, 2, bb2)    // t=2
  GSTEP(5, 1, bb2, 3, bb0)    // t=3
  GSTEP(6, 2, bb0, 0, bb1)    // t=4
  GSTEP(7, 3, bb1, 1, bb2)    // t=5
  GSTEP(8, 0, bb2, 2, bb0)    // t=6
  GSTEP(9, 1, bb0, 3, bb1)    // t=7
  GSTEP(10, 2, bb1, 0, bb2)   // t=8
  GSTEP(11, 3, bb2, 1, bb0)   // t=9
  GSTEP(12, 0, bb0, 2, bb1)   // t=10
  GSTEP(13, 1, bb1, 3, bb2)   // t=11
  GSTEP(14, 2, bb2, 0, bb0)   // t=12
  GSTEP(15, 3, bb0, 1, bb1)   // t=13
  GSTEP(16, 0, bb1, 2, bb2)   // t=14
  GSTEP(17, 1, bb2, 3, bb0)   // t=15
  GSTEP(18, 2, bb0, 0, bb1)   // t=16
  GSTEP(19, 3, bb1, 1, bb2)   // t=17
  GSTEP(20, 0, bb2, 2, bb0)   // t=18
  GSTEP(21, 1, bb0, 3, bb1)   // t=19
  GSTEP(22, 2, bb1, 0, bb2)   // t=20
  GSTEP(23, 3, bb2, 1, bb0)   // t=21
  GSTEP(24, 0, bb0, 2, bb1)   // t=22
  GSTEP(25, 1, bb1, 3, bb2)   // t=23
  GSTEP(26, 2, bb2, 0, bb0)   // t=24
  GSTEP(27, 3, bb0, 1, bb1)   // t=25
  GSTEP(28, 0, bb1, 2, bb2)   // t=26
  GSTEP(29, 1, bb2, 3, bb0)   // t=27
  GSTEP(30, 2, bb0, 0, bb1)   // t=28
  GSTEP(31, 3, bb1, 1, bb2)   // t=29
  BAR1; VMW(10); BAR1; COMP(2, bb0);   // t=30
  BAR1; VMW(4);  BAR1; COMP(3, bb1);   // t=31

#undef GSTEP
#undef BAR1
#undef VMW

  // ---- epilogue ----
  if (EPI == 0) {
#pragma unroll
    for (int nt = 0; nt < 4; ++nt) {
      int n = n0 + wc * 64 + nt * 16 + c;
      float bv = bias[n];
      int h = n / 192, e = n % 192;
      if (e < 128) {
#pragma unroll
        for (int mt = 0; mt < 4; ++mt) {
          int m_base = m0 + wr * 64 + mt * 16 + g * 4;
          int bb2i = m_base >> 11, s0 = m_base & 2047;
          size_t plane = (size_t)(bb2i * H_ + h) * (S_ * HD_);
          if (e < 64) {
            size_t bp = plane + (size_t)(s0 >> 4) * 1024 + (e >> 3) * 128 + (s0 & 15) * 8 + (e & 7);
#pragma unroll
            for (int r = 0; r < 4; ++r)
              qb[bp + r * 8] = f2bf((acc[mt][nt][r] + bv) * QSCALE);
          } else {
            int ek = e - 64;
            size_t bp = plane + (size_t)(s0 >> 4) * 1024 + (ek >> 3) * 128 + (s0 & 15) * 8 + (ek & 7);
#pragma unroll
            for (int r = 0; r < 4; ++r)
              kb[bp + r * 8] = f2bf(acc[mt][nt][r] + bv);
          }
        }
      } else {
        int hd = e - 128;
#pragma unroll
        for (int mtp = 0; mtp < 2; ++mtp) {
          int mt = mtp * 2;
          int m_base = m0 + wr * 64 + mt * 16 + g * 4;
          int bb2i = m_base >> 11, s0 = m_base & 2047;
          size_t plane = (size_t)(bb2i * H_ + h) * (S_ * HD_);
          size_t bp = plane + (size_t)((hd >> 4) * 64 + (s0 >> 5)) * 512 +
                      ((s0 >> 2) & 3) * 128 + (hd & 15) * 8;
          int4_t pk;
#pragma unroll
          for (int r = 0; r < 4; ++r)
            pk[r] = (int)pack_bf16_trunc(acc[mt][nt][r] + bv, acc[mt + 1][nt][r] + bv);
          *reinterpret_cast<int4_t*>(&vt[bp]) = pk;
        }
      }
    }
  } else {
#pragma unroll
    for (int mt = 0; mt < 4; ++mt) {
#pragma unroll
      for (int nt = 0; nt < 4; ++nt) {
        int n = n0 + wc * 64 + nt * 16 + c;
        float bv = bias[n];
        int m_base = m0 + wr * 64 + mt * 16 + g * 4;
#pragma unroll
        for (int r = 0; r < 4; ++r)
          out[(size_t)(m_base + r) * D_ + n] = acc[mt][nt][r] + bv;
      }
    }
  }
}

// ---------------- causal flash attention: 32-key tiles, packed fragments (r12) ----------------
struct KF32 { short8 f[4]; };

__device__ __forceinline__ void load_kf32(KF32& k, const short* __restrict__ kbh,
                                          int ktb, int lane) {
#pragma unroll
  for (int cc = 0; cc < 2; ++cc)
#pragma unroll
    for (int t = 0; t < 2; ++t)
      k.f[cc * 2 + t] = *reinterpret_cast<const short8*>(
          &kbh[(size_t)(ktb * 2 + t) * 1024 + cc * 512 + lane * 8]);
}

__global__ __launch_bounds__(256, 3) void attn_kernel(
    const short* __restrict__ qb, const short* __restrict__ kb,
    const short* __restrict__ vt, short* __restrict__ av) {
  // LPT dispatch: qt descends with local index -> long blocks launch first.
  const int orig = blockIdx.x;
  const int xcd = orig & 7;
  const int local = orig >> 3;
  const int bh = xcd * 8 + (local & 7);
  const int qt = 15 - (local >> 3);
  const int bb = bh >> 4, h = bh & 15;
  const int tid = threadIdx.x;
  const int lane = tid & 63, wv = tid >> 6;
  const int g = lane >> 4, c = lane & 15;
  const int q0 = qt * 128;
  const int r0 = q0 + wv * 32;

  __shared__ short Ps[4][32 * 40];
  short* Pw = Ps[wv];
  unsigned* Pw32 = reinterpret_cast<unsigned*>(Pw);

  const short* qbh = qb + (size_t)bh * S_ * HD_;
  const short* kbh = kb + (size_t)bh * S_ * HD_;
  const short* vth = vt + (size_t)bh * HD_ * S_;

  short8 ones;
#pragma unroll
  for (int j = 0; j < 8; ++j) ones[j] = (short)0x3F80;

  const f32x4 zero4 = {0.f, 0.f, 0.f, 0.f};

  short8 qf[2][2];
#pragma unroll
  for (int mt = 0; mt < 2; ++mt)
#pragma unroll
    for (int cc = 0; cc < 2; ++cc)
      qf[mt][cc] = *reinterpret_cast<const short8*>(
          &qbh[(size_t)(r0 / 16 + mt) * 1024 + cc * 512 + lane * 8]);

  f32x4 acc_o[2][4];
  f32x4 lacc[2];
#pragma unroll
  for (int mt = 0; mt < 2; ++mt) {
    lacc[mt] = zero4;
#pragma unroll
    for (int nt = 0; nt < 4; ++nt) acc_o[mt][nt] = zero4;
  }

  const int diag = 4 * qt + wv;
  const int nk = diag + 1;

  KF32 kA, kB;
  load_kf32(kA, kbh, 0, lane);

  auto body = [&](int ktb, KF32& kc, KF32& kn) {
    const int k0 = ktb * 32;
    short8 vf[4];
#pragma unroll
    for (int nt = 0; nt < 4; ++nt)
      vf[nt] = *reinterpret_cast<const short8*>(
          &vth[(size_t)(nt * 64 + ktb) * 512 + lane * 8]);
    f32x4 sc[2][2];
#pragma unroll
    for (int mt = 0; mt < 2; ++mt)
#pragma unroll
      for (int t = 0; t < 2; ++t) sc[mt][t] = zero4;
#pragma unroll
    for (int cc = 0; cc < 2; ++cc)
#pragma unroll
      for (int mt = 0; mt < 2; ++mt)
#pragma unroll
        for (int t = 0; t < 2; ++t)
          sc[mt][t] = __builtin_amdgcn_mfma_f32_16x16x32_bf16(
              qf[mt][cc], kc.f[cc * 2 + t], sc[mt][t], 0, 0, 0);
    int ktbn = ktb + 1;
    if (ktbn >= S_ / 32) ktbn = 0;
    load_kf32(kn, kbh, ktbn, lane);
    if (ktb == diag) {
#pragma unroll
      for (int mt = 0; mt < 2; ++mt)
#pragma unroll
        for (int t = 0; t < 2; ++t) {
          const int key = k0 + t * 16 + c;
#pragma unroll
          for (int r = 0; r < 4; ++r) {
            const int qi2 = r0 + mt * 16 + g * 4 + r;
            if (key > qi2) sc[mt][t][r] = -INFINITY;
          }
        }
    }
#pragma unroll
    for (int mt = 0; mt < 2; ++mt)
#pragma unroll
      for (int r = 0; r < 4; ++r) {
        float p0 = __builtin_exp2f(sc[mt][0][r]);
        float p1 = __builtin_exp2f(sc[mt][1][r]);
        Pw32[(mt * 16 + g * 4 + r) * 20 + c] = pack_bf16_trunc(p0, p1);
      }
    short8 pa[2];
#pragma unroll
    for (int mt = 0; mt < 2; ++mt)
      pa[mt] = *reinterpret_cast<const short8*>(&Pw[(mt * 16 + c) * 40 + g * 8]);
#pragma unroll
    for (int mt = 0; mt < 2; ++mt)
      lacc[mt] = __builtin_amdgcn_mfma_f32_16x16x32_bf16(pa[mt], ones, lacc[mt], 0, 0, 0);
#pragma unroll
    for (int mt = 0; mt < 2; ++mt)
#pragma unroll
      for (int nt = 0; nt < 4; ++nt)
        acc_o[mt][nt] = __builtin_amdgcn_mfma_f32_16x16x32_bf16(
            pa[mt], vf[nt], acc_o[mt][nt], 0, 0, 0);
  };

  int ktb = 0;
  for (; ktb + 1 < nk; ktb += 2) {
    body(ktb,     kA, kB);
    body(ktb + 1, kB, kA);
  }
  if (ktb < nk) body(ktb, kA, kB);

#pragma unroll
  for (int mt = 0; mt < 2; ++mt) {
    float inv[4];
#pragma unroll
    for (int r = 0; r < 4; ++r) inv[r] = 1.0f / lacc[mt][r];
#pragma unroll
    for (int nt = 0; nt < 4; ++nt)
#pragma unroll
      for (int r = 0; r < 4; ++r) {
        int R = r0 + mt * 16 + g * 4 + r;
        av[(size_t)(bb * S_ + R) * D_ + h * HD_ + nt * 16 + c] =
            f2bf(acc_o[mt][nt][r] * inv[r]);
      }
  }
}

extern "C" void kernel_launch(void* const* d_in, const int* in_sizes, int n_in,
                              void* d_out, int out_size, void* d_ws, size_t ws_size,
                              hipStream_t stream) {
  const float* x    = (const float*)d_in[0];
  const float* Wqkv = (const float*)d_in[1];
  const float* bqkv = (const float*)d_in[2];
  const float* Wo   = (const float*)d_in[3];
  const float* bo   = (const float*)d_in[4];
  float* out = (float*)d_out;

  const size_t NTOK = (size_t)B_ * H_ * S_ * HD_;  // 8,388,608
  short* xb    = (short*)d_ws;                     // 16 MB
  short* wqkvt = xb + (size_t)M_TOK * D_;          // 6 MB (packed)
  short* wot   = wqkvt + (size_t)3072 * 1024;      // 2 MB (packed)
  short* qb    = wot + (size_t)1024 * 1024;        // 16 MB
  short* kb    = qb + NTOK;                        // 16 MB
  short* vt    = kb + NTOK;                        // 16 MB
  short* av    = xb;                               // alias: xb dead after qkv GEMM

  conv_x_kernel   <<<4096, 256, 0, stream>>>(x, xb);
  conv_wqkv_kernel<<<dim3(16, 32), 256, 0, stream>>>(Wqkv, wqkvt);
  conv_wo_kernel  <<<dim3(32, 8), 256, 0, stream>>>(Wo, wot);
  gemm4_kernel<0> <<<dim3(64, 24), 256, 0, stream>>>(xb, wqkvt, bqkv, qb, kb, vt, nullptr);
  attn_kernel     <<<1024, 256, 0, stream>>>(qb, kb, vt, av);
  gemm4_kernel<1> <<<dim3(64, 8), 256, 0, stream>>>(av, wot, bo, nullptr, nullptr, nullptr, out);
}